// Round 1
// baseline (43.791 us; speedup 1.0000x reference)
//
#include <hip/hip_runtime.h>

// Problem constants (match reference)
constexpr int B = 8;
constexpr int T = 4096;
constexpr int D = 768;
constexpr int W = 2048;
constexpr int MAXW = 8;

// One block per (b, w) output row. 192 threads * float4 = 768 floats = one row.
__global__ __launch_bounds__(192) void window_mean_kernel(
    const float* __restrict__ features,   // [B, T, D]
    const int*   __restrict__ begins,     // [B, W]
    const int*   __restrict__ ends,       // [B, W]
    float*       __restrict__ out)        // [B, W, D]
{
    const int row = blockIdx.x;           // b * W + w
    const int b   = row >> 11;            // W = 2048 = 2^11
    const int tid = threadIdx.x;          // 0..191

    const int beg = begins[row];
    const int end = ends[row];
    int len = end - beg;
    if (len > MAXW) len = MAXW;
    const int cnt = (len < 1) ? 1 : len;

    const float* base = features + ((size_t)b * T + (size_t)beg) * D + (size_t)tid * 4;

    float4 acc = make_float4(0.f, 0.f, 0.f, 0.f);
    for (int i = 0; i < len; ++i) {
        float4 v = *reinterpret_cast<const float4*>(base + (size_t)i * D);
        acc.x += v.x; acc.y += v.y; acc.z += v.z; acc.w += v.w;
    }

    const float inv = 1.0f / (float)cnt;
    acc.x *= inv; acc.y *= inv; acc.z *= inv; acc.w *= inv;

    *reinterpret_cast<float4*>(out + (size_t)row * D + (size_t)tid * 4) = acc;
}

extern "C" void kernel_launch(void* const* d_in, const int* in_sizes, int n_in,
                              void* d_out, int out_size, void* d_ws, size_t ws_size,
                              hipStream_t stream) {
    const float* features = (const float*)d_in[0];
    const int*   begins   = (const int*)d_in[1];
    const int*   ends     = (const int*)d_in[2];
    float*       out      = (float*)d_out;

    dim3 grid(B * W);
    dim3 block(192);
    window_mean_kernel<<<grid, block, 0, stream>>>(features, begins, ends, out);
}

// Round 2
// 29.040 us; speedup vs baseline: 1.5079x; 1.5079x over previous
//
#include <hip/hip_runtime.h>

// Problem constants (match reference)
constexpr int B = 8;
constexpr int T = 4096;
constexpr int D = 768;          // 768 floats = 192 float4
constexpr int W = 2048;
constexpr int MAXW = 8;
constexpr int ROWS_PER_BLOCK = 4;   // one wave per output row
constexpr int NXCD = 8;

// Block = 256 threads = 4 waves; wave w handles output row blk*4 + w.
// Lane j loads float4 indices j, j+64, j+128 of each 192-float4 source row
// -> three perfectly coalesced 1KB transactions per row.
__global__ __launch_bounds__(256) void window_mean_kernel(
    const float* __restrict__ features,   // [B, T, D]
    const int*   __restrict__ begins,     // [B, W]
    const int*   __restrict__ ends,       // [B, W]
    float*       __restrict__ out)        // [B, W, D]
{
    // XCD-aware swizzle: grid = 4096 = 8 XCDs * 512 blocks. Blocks with the
    // same (blockIdx % 8) share an XCD (round-robin dispatch); give each XCD
    // one contiguous 512-block chunk = exactly one batch (2048 windows).
    const int grid = gridDim.x;                 // 4096
    const int cpx  = grid / NXCD;               // 512
    const int blk  = (blockIdx.x % NXCD) * cpx + blockIdx.x / NXCD;

    const int wave = threadIdx.x >> 6;          // 0..3
    const int lane = threadIdx.x & 63;          // 0..63

    const int row = blk * ROWS_PER_BLOCK + wave;   // b * W + w
    const int b   = row >> 11;                      // W = 2048 = 2^11

    const int beg = begins[row];
    const int end = ends[row];
    int len = end - beg;
    if (len > MAXW) len = MAXW;
    const int cnt = (len < 1) ? 1 : len;

    const float4* base = reinterpret_cast<const float4*>(
        features + ((size_t)b * T + (size_t)beg) * D);

    float4 a0 = make_float4(0.f, 0.f, 0.f, 0.f);
    float4 a1 = a0, a2 = a0;

    // len is wave-uniform (same row for all 64 lanes) -> no divergence.
    for (int i = 0; i < len; ++i) {
        const float4* p = base + (size_t)i * (D / 4);
        float4 v0 = p[lane];
        float4 v1 = p[lane + 64];
        float4 v2 = p[lane + 128];
        a0.x += v0.x; a0.y += v0.y; a0.z += v0.z; a0.w += v0.w;
        a1.x += v1.x; a1.y += v1.y; a1.z += v1.z; a1.w += v1.w;
        a2.x += v2.x; a2.y += v2.y; a2.z += v2.z; a2.w += v2.w;
    }

    const float inv = 1.0f / (float)cnt;
    a0.x *= inv; a0.y *= inv; a0.z *= inv; a0.w *= inv;
    a1.x *= inv; a1.y *= inv; a1.z *= inv; a1.w *= inv;
    a2.x *= inv; a2.y *= inv; a2.z *= inv; a2.w *= inv;

    float4* o = reinterpret_cast<float4*>(out + (size_t)row * D);
    o[lane]       = a0;
    o[lane + 64]  = a1;
    o[lane + 128] = a2;
}

extern "C" void kernel_launch(void* const* d_in, const int* in_sizes, int n_in,
                              void* d_out, int out_size, void* d_ws, size_t ws_size,
                              hipStream_t stream) {
    const float* features = (const float*)d_in[0];
    const int*   begins   = (const int*)d_in[1];
    const int*   ends     = (const int*)d_in[2];
    float*       out      = (float*)d_out;

    dim3 grid((B * W) / ROWS_PER_BLOCK);   // 4096
    dim3 block(256);
    window_mean_kernel<<<grid, block, 0, stream>>>(features, begins, ends, out);
}

// Round 4
// 27.426 us; speedup vs baseline: 1.5967x; 1.0588x over previous
//
#include <hip/hip_runtime.h>

// Problem constants (match reference)
constexpr int B = 8;
constexpr int T = 4096;
constexpr int D = 768;          // 768 floats = 192 float4
constexpr int W = 2048;
constexpr int MAXW = 8;
constexpr int ROWS_PER_BLOCK = 4;   // one wave per output row
constexpr int NXCD = 8;

// Native clang vector type — __builtin_nontemporal_store requires it
// (HIP_vector_type<float,4> is a struct and is rejected).
typedef float f32x4 __attribute__((ext_vector_type(4)));

// Block = 256 threads = 4 waves; wave w handles output row blk*4 + w.
// Lane j loads float4 indices j, j+64, j+128 of each 192-float4 source row.
// Since begins < T-8 by construction, all 8 candidate rows are in-bounds:
// load them ALL unconditionally (24 independent loads in flight), then
// accumulate with 0/1 weights. No runtime-trip-count loop, max MLP.
__global__ __launch_bounds__(256) void window_mean_kernel(
    const float* __restrict__ features,   // [B, T, D]
    const int*   __restrict__ begins,     // [B, W]
    const int*   __restrict__ ends,       // [B, W]
    float*       __restrict__ out)        // [B, W, D]
{
    // XCD-aware swizzle: grid = 4096 = 8 XCDs * 512 blocks; each XCD gets one
    // contiguous 512-block chunk = exactly one batch (12.6 MB feature slice).
    const int cpx = gridDim.x / NXCD;           // 512
    const int blk = (blockIdx.x % NXCD) * cpx + blockIdx.x / NXCD;

    const int wave = threadIdx.x >> 6;          // 0..3
    const int lane = threadIdx.x & 63;          // 0..63

    const int row = blk * ROWS_PER_BLOCK + wave;   // b * W + w
    const int b   = row >> 11;                      // W = 2048 = 2^11

    const int beg = begins[row];
    int len = ends[row] - beg;                  // guaranteed 1..8
    if (len > MAXW) len = MAXW;
    const float inv = 1.0f / (float)((len < 1) ? 1 : len);

    const f32x4* base = reinterpret_cast<const f32x4*>(
        features + ((size_t)b * T + (size_t)beg) * D);

    // Load all 8 rows up front: 24 independent 1KB wave-transactions.
    f32x4 v[MAXW][3];
#pragma unroll
    for (int i = 0; i < MAXW; ++i) {
        const f32x4* p = base + (size_t)i * (D / 4);
        v[i][0] = p[lane];
        v[i][1] = p[lane + 64];
        v[i][2] = p[lane + 128];
    }

    f32x4 a0 = (f32x4)(0.f);
    f32x4 a1 = (f32x4)(0.f);
    f32x4 a2 = (f32x4)(0.f);
#pragma unroll
    for (int i = 0; i < MAXW; ++i) {
        const float w = (i < len) ? 1.0f : 0.0f;
        a0 += v[i][0] * w;
        a1 += v[i][1] * w;
        a2 += v[i][2] * w;
    }

    a0 *= inv; a1 *= inv; a2 *= inv;

    // Non-temporal stores: don't let 50 MB of output evict the feature
    // working set from the 4 MB/XCD L2s (reads re-use it heavily).
    f32x4* o = reinterpret_cast<f32x4*>(out + (size_t)row * D);
    __builtin_nontemporal_store(a0, &o[lane]);
    __builtin_nontemporal_store(a1, &o[lane + 64]);
    __builtin_nontemporal_store(a2, &o[lane + 128]);
}

extern "C" void kernel_launch(void* const* d_in, const int* in_sizes, int n_in,
                              void* d_out, int out_size, void* d_ws, size_t ws_size,
                              hipStream_t stream) {
    const float* features = (const float*)d_in[0];
    const int*   begins   = (const int*)d_in[1];
    const int*   ends     = (const int*)d_in[2];
    float*       out      = (float*)d_out;

    dim3 grid((B * W) / ROWS_PER_BLOCK);   // 4096
    dim3 block(256);
    window_mean_kernel<<<grid, block, 0, stream>>>(features, begins, ends, out);
}